// Round 4
// baseline (588.291 us; speedup 1.0000x reference)
//
#include <hip/hip_runtime.h>

// (V, D, H, L, E) = (50000, 128, 128, 4, 160000)
#define V_NODES 50000
#define NEDGE   160000
#define NSEG    (8 * V_NODES)          // 400000 (g,node) segments

typedef __bf16 bf16;
typedef __attribute__((ext_vector_type(8))) __bf16 bf16x8;
typedef __attribute__((ext_vector_type(4))) __bf16 bf16x4;
typedef __attribute__((ext_vector_type(2))) __bf16 bf16x2;
typedef __attribute__((ext_vector_type(4))) float  f32x4;

__device__ __forceinline__ int clampV(int n) {
  unsigned u = (unsigned)n;
  return (int)(u < (unsigned)V_NODES ? u : (unsigned)(V_NODES - 1));
}

__device__ __forceinline__ float bflo(unsigned u) {
  return __builtin_bit_cast(float, u << 16);
}
__device__ __forceinline__ float bfhi(unsigned u) {
  return __builtin_bit_cast(float, u & 0xffff0000u);
}

// ---------------- prep kernels: fp32 -> bf16 (weights transposed) ----------

__global__ __launch_bounds__(256) void prep_emb_k(const float* __restrict__ in,
                                                  bf16* __restrict__ out) {
  int i = blockIdx.x * 256 + threadIdx.x;
  float4 v = ((const float4*)in)[i];
  bf16x4 o = {(bf16)v.x, (bf16)v.y, (bf16)v.z, (bf16)v.w};
  *(bf16x4*)(out + (size_t)i * 4) = o;
}

__global__ __launch_bounds__(256) void prep_w1_k(const float* __restrict__ in,
                                                 bf16* __restrict__ out) {
  int idx = blockIdx.x * 256 + threadIdx.x;         // 262144
  int n = idx & 127, k = (idx >> 7) & 255, g = idx >> 15;
  out[(((g << 7) + n) << 8) + k] = (bf16)in[idx];   // w1t[g][n][k]
}

__global__ __launch_bounds__(256) void prep_w2_k(const float* __restrict__ in,
                                                 bf16* __restrict__ out) {
  int idx = blockIdx.x * 256 + threadIdx.x;         // 131072
  int n = idx & 127, k = (idx >> 7) & 127, g = idx >> 14;
  out[(((g << 7) + n) << 7) + k] = (bf16)in[idx];   // w2t[g][n][k]
}

__global__ __launch_bounds__(256) void relu_k(float* __restrict__ out) {
  int i = blockIdx.x * 256 + threadIdx.x;
  float4 v = ((float4*)out)[i];
  v.x = fmaxf(v.x, 0.f); v.y = fmaxf(v.y, 0.f);
  v.z = fmaxf(v.z, 0.f); v.w = fmaxf(v.w, 0.f);
  ((float4*)out)[i] = v;
}

// ---------------- CSR build ------------------------------------------------

__global__ __launch_bounds__(256) void hist_k(
    const int* __restrict__ a0, const int* __restrict__ a1,
    const int* __restrict__ a2, const int* __restrict__ a3,
    int* __restrict__ counts) {
  int e = blockIdx.x * 256 + threadIdx.x;    // 0..159999
  int g = blockIdx.y;                        // 0..7
  int l = g >> 1, ep = g & 1;
  const int* adj = (l == 0) ? a0 : (l == 1) ? a1 : (l == 2) ? a2 : a3;
  int tgt = clampV(adj[2 * e + ep]);
  atomicAdd(&counts[g * V_NODES + tgt], 1);
}

// scan_a: 512 elems/block, exclusive within block, emit block sums
__global__ __launch_bounds__(256) void scan_a_k(const int* __restrict__ counts,
                                                int* __restrict__ offs,
                                                int* __restrict__ bsums) {
  __shared__ int sh[256];
  int t = threadIdx.x, base = blockIdx.x * 512;
  int e0 = base + 2 * t, e1 = e0 + 1;
  int a = (e0 < NSEG) ? counts[e0] : 0;
  int b = (e1 < NSEG) ? counts[e1] : 0;
  int s = a + b;
  sh[t] = s;
  __syncthreads();
  #pragma unroll
  for (int d = 1; d < 256; d <<= 1) {
    int v = (t >= d) ? sh[t - d] : 0;
    __syncthreads();
    sh[t] += v;
    __syncthreads();
  }
  int excl = sh[t] - s;
  if (e0 < NSEG) offs[e0] = excl;
  if (e1 < NSEG) offs[e1] = excl + a;
  if (t == 255) bsums[blockIdx.x] = sh[255];
}

#define NBLK_SCAN 782   // ceil(400000/512)

__global__ __launch_bounds__(256) void scan_b_k(int* __restrict__ bsums,
                                                int* __restrict__ offs) {
  __shared__ int sh[NBLK_SCAN];
  int t = threadIdx.x;
  for (int i = t; i < NBLK_SCAN; i += 256) sh[i] = bsums[i];
  __syncthreads();
  if (t == 0) {
    int run = 0;
    for (int i = 0; i < NBLK_SCAN; ++i) { int v = sh[i]; sh[i] = run; run += v; }
    offs[NSEG] = run;        // total = 1,280,000
  }
  __syncthreads();
  for (int i = t; i < NBLK_SCAN; i += 256) bsums[i] = sh[i];
}

__global__ __launch_bounds__(256) void scan_c_k(int* __restrict__ offs,
                                                const int* __restrict__ bsums) {
  int i = blockIdx.x * 256 + threadIdx.x;
  if (i < NSEG) offs[i] += bsums[i >> 9];
}

// scatter packed (src,dst) pairs -> removes the adj[] indirection in aggf
__global__ __launch_bounds__(256) void scatter_ids2_k(
    const int* __restrict__ a0, const int* __restrict__ a1,
    const int* __restrict__ a2, const int* __restrict__ a3,
    const int* __restrict__ offs, int* __restrict__ cursor,
    int2* __restrict__ ids2) {
  int e = blockIdx.x * 256 + threadIdx.x;
  int g = blockIdx.y;
  int l = g >> 1, ep = g & 1;
  const int* adj = (l == 0) ? a0 : (l == 1) ? a1 : (l == 2) ? a2 : a3;
  int2 pr = ((const int2*)adj)[e];
  int src = clampV(pr.x), dst = clampV(pr.y);
  int tgt = ep ? dst : src;
  int seg = g * V_NODES + tgt;
  int pos = offs[seg] + atomicAdd(&cursor[seg], 1);
  ids2[pos] = make_int2(src, dst);
}

// ---------------- X precompute: register-resident W1^T, 625 blocks ---------
// Xa[g][v] = emb[v] @ W1[g][0:128,:], Xb[g][v] = emb[v] @ W1[g][128:256,:]
// wave w: h2 = w>>1 (Xa/Xb K-half), dh = w&1 (64 n-dims). 5 tiles x 16 nodes
// per block = 80 nodes; grid (625, GG).

__global__ __launch_bounds__(256) void xgemm2_k(const bf16* __restrict__ embB,
                                                const bf16* __restrict__ w1t,
                                                bf16* __restrict__ Xab,
                                                int gbase) {
  const int tid = threadIdx.x, w = tid >> 6, lane = tid & 63;
  const int l15 = lane & 15, q = lane >> 4;
  const int h2 = w >> 1, dh = w & 1;
  const int slot = blockIdx.y, g = gbase + slot;

  bf16x8 wA[4][4];
  const bf16* __restrict__ w1g = w1t + (size_t)g * 32768;
  #pragma unroll
  for (int mb = 0; mb < 4; ++mb)
    #pragma unroll
    for (int kb = 0; kb < 4; ++kb)
      wA[mb][kb] = *(const bf16x8*)(w1g + (size_t)(dh * 64 + mb * 16 + l15) * 256 +
                                    h2 * 128 + kb * 32 + q * 8);

  bf16* __restrict__ Xh = Xab + (size_t)slot * 12800000 + (size_t)h2 * 6400000;

  #pragma unroll
  for (int t = 0; t < 5; ++t) {
    const int node = blockIdx.x * 80 + t * 16 + l15;
    bf16x8 b[4];
    #pragma unroll
    for (int kb = 0; kb < 4; ++kb)
      b[kb] = *(const bf16x8*)(embB + (size_t)node * 128 + kb * 32 + q * 8);

    f32x4 acc[4] = {};
    #pragma unroll
    for (int kb = 0; kb < 4; ++kb)
      #pragma unroll
      for (int mb = 0; mb < 4; ++mb)
        acc[mb] = __builtin_amdgcn_mfma_f32_16x16x32_bf16(wA[mb][kb], b[kb], acc[mb], 0, 0, 0);

    bf16* basep = Xh + (size_t)node * 128 + dh * 64 + q * 4;
    #pragma unroll
    for (int mb = 0; mb < 4; ++mb) {
      bf16x4 o = {(bf16)acc[mb][0], (bf16)acc[mb][1],
                  (bf16)acc[mb][2], (bf16)acc[mb][3]};
      *(bf16x4*)(basep + mb * 16) = o;
    }
  }
}

// ---------------- fused aggregate (v3): half-wave split --------------------
// Hagg[g][node] = sum_edges relu(Xa[src] + Xb[dst]); own side loop-invariant.
// Half-wave h processes edges beg+h, beg+h+2, ... : 32 lanes x 8B = full row,
// 2 edges in flight per wave. Cross-half merge via shfl_xor(32).

__global__ __launch_bounds__(256) void aggf3_k(
    const bf16* __restrict__ Xab,
    const int* __restrict__ offs, const int2* __restrict__ ids2,
    bf16* __restrict__ HaggB, int gbase) {
  const int wv = threadIdx.x >> 6, lane = threadIdx.x & 63;
  const int h = lane >> 5, m = lane & 31;
  const int node = blockIdx.x * 4 + wv;
  const int slot = blockIdx.y, g = gbase + slot;
  const int ep = g & 1;
  const bf16* __restrict__ Xa = Xab + (size_t)slot * 12800000;
  const bf16* __restrict__ Xb = Xa + 6400000;
  const bf16* __restrict__ own = ep ? Xb : Xa;   // target side
  const bf16* __restrict__ oth = ep ? Xa : Xb;   // gathered side
  const int seg = g * V_NODES + node;
  const int beg = offs[seg], end = offs[seg + 1];

  uint2 uo = *(const uint2*)(own + (size_t)node * 128 + m * 4);
  const float o0 = bflo(uo.x), o1 = bfhi(uo.x);
  const float o2 = bflo(uo.y), o3 = bfhi(uo.y);

  float s0 = 0.f, s1 = 0.f, s2 = 0.f, s3 = 0.f;
  for (int i = beg + h; i < end; i += 2) {
    int2 p = ids2[i];
    int n = ep ? p.x : p.y;      // the non-target endpoint
    uint2 u = *(const uint2*)(oth + (size_t)n * 128 + m * 4);
    s0 += fmaxf(o0 + bflo(u.x), 0.f);
    s1 += fmaxf(o1 + bfhi(u.x), 0.f);
    s2 += fmaxf(o2 + bflo(u.y), 0.f);
    s3 += fmaxf(o3 + bfhi(u.y), 0.f);
  }
  s0 += __shfl_xor(s0, 32);
  s1 += __shfl_xor(s1, 32);
  s2 += __shfl_xor(s2, 32);
  s3 += __shfl_xor(s3, 32);
  if (h == 0) {
    bf16x4 st = {(bf16)s0, (bf16)s1, (bf16)s2, (bf16)s3};
    *(bf16x4*)(HaggB + ((size_t)g * V_NODES + node) * 128 + m * 4) = st;
  }
}

// ---------------- dense GEMM2 (single launch, all 8 groups) ----------------
// out = relu(sum_g Hagg[g] @ W2[g]). Wave: 32 rows x 32 cols (mt=2, nb-pair
// = wave id). Block: 32 rows x 128 cols. Grid 1563 -> 6252 waves (~6/SIMD).

__global__ __launch_bounds__(256) void gemm2f_k(const bf16* __restrict__ HaggB,
                                                const bf16* __restrict__ w2t,
                                                float* __restrict__ out) {
  const int tid = threadIdx.x, wv = tid >> 6, lane = tid & 63;
  const int l15 = lane & 15, q = lane >> 4;
  const int v0 = blockIdx.x * 32;

  f32x4 acc[2][2] = {};     // [mt][t]
  for (int g = 0; g < 8; ++g) {
    const bf16* __restrict__ Hg = HaggB + (size_t)g * 6400000;
    const bf16* __restrict__ Wb = w2t + (size_t)g * 16384;
    bf16x8 a[2][4];
    #pragma unroll
    for (int mt = 0; mt < 2; ++mt) {
      int vr = v0 + mt * 16 + l15;
      int vc = vr < V_NODES ? vr : V_NODES - 1;
      #pragma unroll
      for (int kb = 0; kb < 4; ++kb)
        a[mt][kb] = *(const bf16x8*)(Hg + (size_t)vc * 128 + kb * 32 + q * 8);
    }
    #pragma unroll
    for (int kb = 0; kb < 4; ++kb) {
      #pragma unroll
      for (int t = 0; t < 2; ++t) {
        int n = (wv * 2 + t) * 16 + l15;
        bf16x8 b = *(const bf16x8*)(Wb + (size_t)n * 128 + kb * 32 + q * 8);
        #pragma unroll
        for (int mt = 0; mt < 2; ++mt)
          acc[mt][t] = __builtin_amdgcn_mfma_f32_16x16x32_bf16(a[mt][kb], b, acc[mt][t], 0, 0, 0);
      }
    }
  }

  #pragma unroll
  for (int mt = 0; mt < 2; ++mt)
    #pragma unroll
    for (int r = 0; r < 4; ++r) {
      int row = v0 + mt * 16 + q * 4 + r;
      if (row < V_NODES) {
        #pragma unroll
        for (int t = 0; t < 2; ++t) {
          int col = (wv * 2 + t) * 16 + l15;
          out[(size_t)row * 128 + col] = fmaxf(acc[mt][t][r], 0.f);
        }
      }
    }
}

// ---------------- fallback edge kernel (round-0, proven 637us) -------------

__global__ __launch_bounds__(256) void edge_k(
    const bf16* __restrict__ embB,
    const int* __restrict__ a0, const int* __restrict__ a1,
    const int* __restrict__ a2, const int* __restrict__ a3,
    const bf16* __restrict__ w1t, const bf16* __restrict__ w2t,
    float* __restrict__ out) {

  __shared__ __attribute__((aligned(16))) bf16 w1_lds[128 * 256];
  __shared__ __attribute__((aligned(16))) bf16 h_lds[64 * 128];

  const int tid = threadIdx.x;
  const int g  = blockIdx.x >> 6;
  const int bs = blockIdx.x & 63;
  const int l = g >> 1, ep = g & 1;
  const int* __restrict__ adj = (l == 0) ? a0 : (l == 1) ? a1 : (l == 2) ? a2 : a3;

  {
    const uint4* w1g = (const uint4*)(w1t + (size_t)g * 128 * 256);
    #pragma unroll
    for (int i = 0; i < 16; ++i) {
      int j = i * 256 + tid;
      int n = j >> 5, c = j & 31;
      *(uint4*)(&w1_lds[n * 256 + ((c ^ (n & 7)) << 3)]) = w1g[j];
    }
  }
  __syncthreads();

  const int w    = tid >> 6;
  const int lane = tid & 63;
  const int wr = w >> 1, wc = w & 1;
  const int l15 = lane & 15, q = lane >> 4;
  const bf16* __restrict__ w2g = w2t + (size_t)g * 128 * 128;

  for (int t = bs; t < 2500; t += 64) {
    const int ebase = t * 64;
    int2 pr0 = ((const int2*)adj)[ebase + 32 * wr + l15];
    int2 pr1 = ((const int2*)adj)[ebase + 32 * wr + 16 + l15];
    pr0.x = clampV(pr0.x); pr0.y = clampV(pr0.y);
    pr1.x = clampV(pr1.x); pr1.y = clampV(pr1.y);

    f32x4 acc[2][4] = {};
    #pragma unroll
    for (int kb = 0; kb < 8; ++kb) {
      const int k = kb * 32 + q * 8;
      const int klo = k & 127;
      const int n0 = (kb < 4) ? pr0.x : pr0.y;
      const int n1 = (kb < 4) ? pr1.x : pr1.y;
      bf16x8 a[2], b[4];
      a[0] = *(const bf16x8*)(embB + (size_t)n0 * 128 + klo);
      a[1] = *(const bf16x8*)(embB + (size_t)n1 * 128 + klo);
      const int csw = ((kb << 2) + q);
      #pragma unroll
      for (int nt = 0; nt < 4; ++nt) {
        int n = 64 * wc + 16 * nt + l15;
        b[nt] = *(const bf16x8*)(&w1_lds[n * 256 + ((csw ^ (l15 & 7)) << 3)]);
      }
      #pragma unroll
      for (int mt = 0; mt < 2; ++mt)
        #pragma unroll
        for (int nt = 0; nt < 4; ++nt)
          acc[mt][nt] = __builtin_amdgcn_mfma_f32_16x16x32_bf16(a[mt], b[nt], acc[mt][nt], 0, 0, 0);
    }

    __syncthreads();
    #pragma unroll
    for (int mt = 0; mt < 2; ++mt)
      #pragma unroll
      for (int nt = 0; nt < 4; ++nt)
        #pragma unroll
        for (int r = 0; r < 4; ++r) {
          float v = acc[mt][nt][r];
          v = v > 0.f ? v : 0.f;
          int row = 32 * wr + 16 * mt + 4 * q + r;
          int col = 64 * wc + 16 * nt + l15;
          int c = col >> 3;
          h_lds[row * 128 + (((c ^ (row & 7)) << 3) | (col & 7))] = (bf16)v;
        }
    __syncthreads();

    f32x4 acc2[2][4] = {};
    #pragma unroll
    for (int kb = 0; kb < 4; ++kb) {
      const int k = kb * 32 + q * 8;
      const int csw = (kb << 2) + q;
      bf16x8 a[2], b[4];
      #pragma unroll
      for (int mt = 0; mt < 2; ++mt) {
        int row = 32 * wr + 16 * mt + l15;
        a[mt] = *(const bf16x8*)(&h_lds[row * 128 + ((csw ^ (row & 7)) << 3)]);
      }
      #pragma unroll
      for (int nt = 0; nt < 4; ++nt) {
        int n = 64 * wc + 16 * nt + l15;
        b[nt] = *(const bf16x8*)(w2g + n * 128 + k);
      }
      #pragma unroll
      for (int mt = 0; mt < 2; ++mt)
        #pragma unroll
        for (int nt = 0; nt < 4; ++nt)
          acc2[mt][nt] = __builtin_amdgcn_mfma_f32_16x16x32_bf16(a[mt], b[nt], acc2[mt][nt], 0, 0, 0);
    }

    #pragma unroll
    for (int mt = 0; mt < 2; ++mt)
      #pragma unroll
      for (int r = 0; r < 4; ++r) {
        int row = 32 * wr + 16 * mt + 4 * q + r;
        int2 pr = ((const int2*)adj)[ebase + row];
        int node = clampV(ep ? pr.y : pr.x);
        float* basep = out + (size_t)node * 128 + 64 * wc + l15;
        #pragma unroll
        for (int nt = 0; nt < 4; ++nt)
          unsafeAtomicAdd(basep + 16 * nt, acc2[mt][nt][r]);
      }
  }
}

// ---------------- host launch ----------------------------------------------

extern "C" void kernel_launch(void* const* d_in, const int* in_sizes, int n_in,
                              void* d_out, int out_size, void* d_ws, size_t ws_size,
                              hipStream_t stream) {
  const float* emb = (const float*)d_in[0];
  const int* a0 = (const int*)d_in[1];
  const int* a1 = (const int*)d_in[2];
  const int* a2 = (const int*)d_in[3];
  const int* a3 = (const int*)d_in[4];
  const float* W1 = (const float*)d_in[5];
  const float* W2 = (const float*)d_in[6];
  float* out = (float*)d_out;

  char* ws = (char*)d_ws;
  bf16* embB   = (bf16*)(ws);                    // 12,800,000
  bf16* w1t    = (bf16*)(ws + 12800000);         //    524,288
  bf16* w2t    = (bf16*)(ws + 13324288);         //    262,144
  int*  offs   = (int*) (ws + 13586432);         //  1,600,016 (400001 ints + pad)
  int2* ids2   = (int2*)(ws + 15186448);         // 10,240,000
  int*  bsums  = (int*) (ws + 25426448);         //      3,136
  int*  counts = (int*) (ws + 25429584);         //  1,600,000 (reused as cursor)
  bf16* HaggB  = (bf16*)(ws + 27029584);         // 102,400,000 (all 8 groups, bf16)
  bf16* Xab    = (bf16*)(ws + 129429584);        // GG * 25,600,000 (Xa|Xb per g)
  const size_t fixedsz = 129429584;

  prep_emb_k<<<6250, 256, 0, stream>>>(emb, embB);
  prep_w1_k<<<1024, 256, 0, stream>>>(W1, w1t);
  prep_w2_k<<<512, 256, 0, stream>>>(W2, w2t);

  int GG = 0;
  if      (ws_size >= fixedsz + 8ull * 25600000) GG = 8;   // 334.2 MB
  else if (ws_size >= fixedsz + 4ull * 25600000) GG = 4;   // 231.8 MB
  else if (ws_size >= fixedsz + 2ull * 25600000) GG = 2;   // 180.6 MB
  else if (ws_size >= fixedsz + 1ull * 25600000) GG = 1;   // 155.0 MB

  if (GG) {
    // CSR build (all 8 groups at once), pairs packed at scatter time
    hipMemsetAsync(counts, 0, 1600000, stream);
    hist_k<<<dim3(625, 8), 256, 0, stream>>>(a0, a1, a2, a3, counts);
    scan_a_k<<<NBLK_SCAN, 256, 0, stream>>>(counts, offs, bsums);
    scan_b_k<<<1, 256, 0, stream>>>(bsums, offs);
    scan_c_k<<<1563, 256, 0, stream>>>(offs, bsums);
    hipMemsetAsync(counts, 0, 1600000, stream);     // reuse counts as cursor
    scatter_ids2_k<<<dim3(625, 8), 256, 0, stream>>>(a0, a1, a2, a3, offs, counts, ids2);

    for (int gb = 0; gb < 8; gb += GG) {
      xgemm2_k<<<dim3(625, GG), 256, 0, stream>>>(embB, w1t, Xab, gb);
      aggf3_k<<<dim3(12500, GG), 256, 0, stream>>>(Xab, offs, ids2, HaggB, gb);
    }
    gemm2f_k<<<1563, 256, 0, stream>>>(HaggB, w2t, out);
  } else {
    hipMemsetAsync(d_out, 0, 25600000, stream);
    edge_k<<<512, 256, 0, stream>>>(embB, a0, a1, a2, a3, w1t, w2t, out);
    relu_k<<<6250, 256, 0, stream>>>(out);
  }
}

// Round 5
// 503.982 us; speedup vs baseline: 1.1673x; 1.1673x over previous
//
#include <hip/hip_runtime.h>

// (V, D, H, L, E) = (50000, 128, 128, 4, 160000)
#define V_NODES 50000
#define NEDGE   160000
#define NSEG    (8 * V_NODES)          // 400000 (g,node) segments

typedef __bf16 bf16;
typedef __attribute__((ext_vector_type(8))) __bf16 bf16x8;
typedef __attribute__((ext_vector_type(4))) __bf16 bf16x4;
typedef __attribute__((ext_vector_type(2))) __bf16 bf16x2;
typedef __attribute__((ext_vector_type(4))) float  f32x4;

__device__ __forceinline__ int clampV(int n) {
  unsigned u = (unsigned)n;
  return (int)(u < (unsigned)V_NODES ? u : (unsigned)(V_NODES - 1));
}

__device__ __forceinline__ float bflo(unsigned u) {
  return __builtin_bit_cast(float, u << 16);
}
__device__ __forceinline__ float bfhi(unsigned u) {
  return __builtin_bit_cast(float, u & 0xffff0000u);
}

// ---------------- prep kernels: fp32 -> bf16 (weights transposed) ----------

__global__ __launch_bounds__(256) void prep_emb_k(const float* __restrict__ in,
                                                  bf16* __restrict__ out) {
  int i = blockIdx.x * 256 + threadIdx.x;
  float4 v = ((const float4*)in)[i];
  bf16x4 o = {(bf16)v.x, (bf16)v.y, (bf16)v.z, (bf16)v.w};
  *(bf16x4*)(out + (size_t)i * 4) = o;
}

__global__ __launch_bounds__(256) void prep_w1_k(const float* __restrict__ in,
                                                 bf16* __restrict__ out) {
  int idx = blockIdx.x * 256 + threadIdx.x;         // 262144
  int n = idx & 127, k = (idx >> 7) & 255, g = idx >> 15;
  out[(((g << 7) + n) << 8) + k] = (bf16)in[idx];   // w1t[g][n][k]
}

__global__ __launch_bounds__(256) void prep_w2_k(const float* __restrict__ in,
                                                 bf16* __restrict__ out) {
  int idx = blockIdx.x * 256 + threadIdx.x;         // 131072
  int n = idx & 127, k = (idx >> 7) & 127, g = idx >> 14;
  out[(((g << 7) + n) << 7) + k] = (bf16)in[idx];   // w2t[g][n][k]
}

__global__ __launch_bounds__(256) void relu_k(float* __restrict__ out) {
  int i = blockIdx.x * 256 + threadIdx.x;
  float4 v = ((float4*)out)[i];
  v.x = fmaxf(v.x, 0.f); v.y = fmaxf(v.y, 0.f);
  v.z = fmaxf(v.z, 0.f); v.w = fmaxf(v.w, 0.f);
  ((float4*)out)[i] = v;
}

// ---------------- CSR build ------------------------------------------------

__global__ __launch_bounds__(256) void hist_k(
    const int* __restrict__ a0, const int* __restrict__ a1,
    const int* __restrict__ a2, const int* __restrict__ a3,
    int* __restrict__ counts) {
  int e = blockIdx.x * 256 + threadIdx.x;    // 0..159999
  int g = blockIdx.y;                        // 0..7
  int l = g >> 1, ep = g & 1;
  const int* adj = (l == 0) ? a0 : (l == 1) ? a1 : (l == 2) ? a2 : a3;
  int tgt = clampV(adj[2 * e + ep]);
  atomicAdd(&counts[g * V_NODES + tgt], 1);
}

// scan_a: 512 elems/block, exclusive within block, emit block sums
__global__ __launch_bounds__(256) void scan_a_k(const int* __restrict__ counts,
                                                int* __restrict__ offs,
                                                int* __restrict__ bsums) {
  __shared__ int sh[256];
  int t = threadIdx.x, base = blockIdx.x * 512;
  int e0 = base + 2 * t, e1 = e0 + 1;
  int a = (e0 < NSEG) ? counts[e0] : 0;
  int b = (e1 < NSEG) ? counts[e1] : 0;
  int s = a + b;
  sh[t] = s;
  __syncthreads();
  #pragma unroll
  for (int d = 1; d < 256; d <<= 1) {
    int v = (t >= d) ? sh[t - d] : 0;
    __syncthreads();
    sh[t] += v;
    __syncthreads();
  }
  int excl = sh[t] - s;
  if (e0 < NSEG) offs[e0] = excl;
  if (e1 < NSEG) offs[e1] = excl + a;
  if (t == 255) bsums[blockIdx.x] = sh[255];
}

#define NBLK_SCAN 782   // ceil(400000/512)

__global__ __launch_bounds__(256) void scan_b_k(int* __restrict__ bsums,
                                                int* __restrict__ offs) {
  __shared__ int sh[NBLK_SCAN];
  int t = threadIdx.x;
  for (int i = t; i < NBLK_SCAN; i += 256) sh[i] = bsums[i];
  __syncthreads();
  if (t == 0) {
    int run = 0;
    for (int i = 0; i < NBLK_SCAN; ++i) { int v = sh[i]; sh[i] = run; run += v; }
    offs[NSEG] = run;        // total = 1,280,000
  }
  __syncthreads();
  for (int i = t; i < NBLK_SCAN; i += 256) bsums[i] = sh[i];
}

__global__ __launch_bounds__(256) void scan_c_k(int* __restrict__ offs,
                                                const int* __restrict__ bsums) {
  int i = blockIdx.x * 256 + threadIdx.x;
  if (i < NSEG) offs[i] += bsums[i >> 9];
}

// scatter packed (src,dst) pairs -> removes the adj[] indirection in aggf
__global__ __launch_bounds__(256) void scatter_ids2_k(
    const int* __restrict__ a0, const int* __restrict__ a1,
    const int* __restrict__ a2, const int* __restrict__ a3,
    const int* __restrict__ offs, int* __restrict__ cursor,
    int2* __restrict__ ids2) {
  int e = blockIdx.x * 256 + threadIdx.x;
  int g = blockIdx.y;
  int l = g >> 1, ep = g & 1;
  const int* adj = (l == 0) ? a0 : (l == 1) ? a1 : (l == 2) ? a2 : a3;
  int2 pr = ((const int2*)adj)[e];
  int src = clampV(pr.x), dst = clampV(pr.y);
  int tgt = ep ? dst : src;
  int seg = g * V_NODES + tgt;
  int pos = offs[seg] + atomicAdd(&cursor[seg], 1);
  ids2[pos] = make_int2(src, dst);
}

// ---------------- X precompute: register-resident W1^T, 625 blocks ---------
// Xa[g][v] = emb[v] @ W1[g][0:128,:], Xb[g][v] = emb[v] @ W1[g][128:256,:]
// wave w: h2 = w>>1 (Xa/Xb K-half), dh = w&1 (64 n-dims). 5 tiles x 16 nodes
// per block = 80 nodes; grid (625, GG).

__global__ __launch_bounds__(256) void xgemm2_k(const bf16* __restrict__ embB,
                                                const bf16* __restrict__ w1t,
                                                bf16* __restrict__ Xab,
                                                int gbase) {
  const int tid = threadIdx.x, w = tid >> 6, lane = tid & 63;
  const int l15 = lane & 15, q = lane >> 4;
  const int h2 = w >> 1, dh = w & 1;
  const int slot = blockIdx.y, g = gbase + slot;

  bf16x8 wA[4][4];
  const bf16* __restrict__ w1g = w1t + (size_t)g * 32768;
  #pragma unroll
  for (int mb = 0; mb < 4; ++mb)
    #pragma unroll
    for (int kb = 0; kb < 4; ++kb)
      wA[mb][kb] = *(const bf16x8*)(w1g + (size_t)(dh * 64 + mb * 16 + l15) * 256 +
                                    h2 * 128 + kb * 32 + q * 8);

  bf16* __restrict__ Xh = Xab + (size_t)slot * 12800000 + (size_t)h2 * 6400000;

  #pragma unroll
  for (int t = 0; t < 5; ++t) {
    const int node = blockIdx.x * 80 + t * 16 + l15;
    bf16x8 b[4];
    #pragma unroll
    for (int kb = 0; kb < 4; ++kb)
      b[kb] = *(const bf16x8*)(embB + (size_t)node * 128 + kb * 32 + q * 8);

    f32x4 acc[4] = {};
    #pragma unroll
    for (int kb = 0; kb < 4; ++kb)
      #pragma unroll
      for (int mb = 0; mb < 4; ++mb)
        acc[mb] = __builtin_amdgcn_mfma_f32_16x16x32_bf16(wA[mb][kb], b[kb], acc[mb], 0, 0, 0);

    bf16* basep = Xh + (size_t)node * 128 + dh * 64 + q * 4;
    #pragma unroll
    for (int mb = 0; mb < 4; ++mb) {
      bf16x4 o = {(bf16)acc[mb][0], (bf16)acc[mb][1],
                  (bf16)acc[mb][2], (bf16)acc[mb][3]};
      *(bf16x4*)(basep + mb * 16) = o;
    }
  }
}

// ---------------- fused aggregate (v4): one segment per HALF-wave ----------
// Hagg[g][node] = sum_edges relu(Xa[src] + Xb[dst]); own side loop-invariant.
// 32 lanes x 8B = full 256B row. Each half-wave owns its own segment ->
// 2 independent latency chains per wave; edge-unroll-2 -> up to 4 gathers in
// flight. Natural full-row store, no shfl, no idle lanes at store.

__global__ __launch_bounds__(256) void aggf4_k(
    const bf16* __restrict__ Xab,
    const int* __restrict__ offs, const int2* __restrict__ ids2,
    bf16* __restrict__ HaggB, int gbase) {
  const int wv = threadIdx.x >> 6, lane = threadIdx.x & 63;
  const int h = lane >> 5, m = lane & 31;
  const int node = blockIdx.x * 8 + wv * 2 + h;
  const int slot = blockIdx.y, g = gbase + slot;
  const int ep = g & 1;
  const bf16* __restrict__ Xa = Xab + (size_t)slot * 12800000;
  const bf16* __restrict__ Xb = Xa + 6400000;
  const bf16* __restrict__ own = ep ? Xb : Xa;   // target side
  const bf16* __restrict__ oth = ep ? Xa : Xb;   // gathered side
  const int seg = g * V_NODES + node;
  const int beg = offs[seg], end = offs[seg + 1];

  uint2 uo = *(const uint2*)(own + (size_t)node * 128 + m * 4);
  const float o0 = bflo(uo.x), o1 = bfhi(uo.x);
  const float o2 = bflo(uo.y), o3 = bfhi(uo.y);

  float s0 = 0.f, s1 = 0.f, s2 = 0.f, s3 = 0.f;
  int i = beg;
  for (; i + 2 <= end; i += 2) {
    int2 p0 = ids2[i];
    int2 p1 = ids2[i + 1];
    int n0 = ep ? p0.x : p0.y;     // the non-target endpoint
    int n1 = ep ? p1.x : p1.y;
    uint2 u0 = *(const uint2*)(oth + (size_t)n0 * 128 + m * 4);
    uint2 u1 = *(const uint2*)(oth + (size_t)n1 * 128 + m * 4);
    s0 += fmaxf(o0 + bflo(u0.x), 0.f) + fmaxf(o0 + bflo(u1.x), 0.f);
    s1 += fmaxf(o1 + bfhi(u0.x), 0.f) + fmaxf(o1 + bfhi(u1.x), 0.f);
    s2 += fmaxf(o2 + bflo(u0.y), 0.f) + fmaxf(o2 + bflo(u1.y), 0.f);
    s3 += fmaxf(o3 + bfhi(u0.y), 0.f) + fmaxf(o3 + bfhi(u1.y), 0.f);
  }
  if (i < end) {
    int2 p = ids2[i];
    int n = ep ? p.x : p.y;
    uint2 u = *(const uint2*)(oth + (size_t)n * 128 + m * 4);
    s0 += fmaxf(o0 + bflo(u.x), 0.f);
    s1 += fmaxf(o1 + bfhi(u.x), 0.f);
    s2 += fmaxf(o2 + bflo(u.y), 0.f);
    s3 += fmaxf(o3 + bfhi(u.y), 0.f);
  }
  bf16x4 st = {(bf16)s0, (bf16)s1, (bf16)s2, (bf16)s3};
  *(bf16x4*)(HaggB + ((size_t)g * V_NODES + node) * 128 + m * 4) = st;
}

// ---------------- dense GEMM2 (LDS-staged A, single launch) ----------------
// out = relu(sum_g Hagg[g] @ W2[g]). Block: 32 rows x 128 cols, 4 waves
// (wave = 32 rows x 32 cols). Per g the 32x128 Hagg tile (8KB) is staged
// ONCE per block: 256 threads x 32B contiguous global load -> XOR-swizzled
// ds_write_b128 (edge_k pattern); all 4 waves read fragments via swizzled
// ds_read_b128 (8 lanes/bank-quad = conflict-free for b128). Next-g loads
// issue before the 2nd barrier (hide HBM latency under MFMA of 6 blocks/CU).

__global__ __launch_bounds__(256) void gemm2p_k(const bf16* __restrict__ HaggB,
                                                const bf16* __restrict__ w2t,
                                                float* __restrict__ out) {
  __shared__ __attribute__((aligned(16))) bf16 a_lds[32 * 128];   // 8KB

  const int tid = threadIdx.x, wv = tid >> 6, lane = tid & 63;
  const int l15 = lane & 15, q = lane >> 4;
  const int v0 = blockIdx.x * 32;

  // staging address (chunk j = 16B): j0 = tid*2, row = tid>>3, c = j&15
  const int srow = tid >> 3, sc0 = (tid & 7) * 2;
  bf16* sp0 = &a_lds[srow * 128 + ((sc0 ^ (srow & 7)) << 3)];
  bf16* sp1 = &a_lds[srow * 128 + (((sc0 + 1) ^ (srow & 7)) << 3)];

  // preload g=0 tile (32B/thread, contiguous 8KB/block; overrun past row
  // 49999 reads into adjacent ws buffers -> discarded by store guard)
  const uint4* Hg = (const uint4*)(HaggB + (size_t)v0 * 128);
  uint4 s0 = Hg[tid * 2], s1 = Hg[tid * 2 + 1];

  f32x4 acc[2][2] = {};     // [mt][t]
  for (int g = 0; g < 8; ++g) {
    __syncthreads();                      // prior iteration's ds_reads done
    *(uint4*)sp0 = s0;
    *(uint4*)sp1 = s1;
    if (g < 7) {                          // issue next-g loads early
      const uint4* Hn = (const uint4*)(HaggB + (size_t)(g + 1) * 6400000 +
                                       (size_t)v0 * 128);
      s0 = Hn[tid * 2];
      s1 = Hn[tid * 2 + 1];
    }
    __syncthreads();                      // staged tile visible

    const bf16* __restrict__ Wb = w2t + (size_t)g * 16384;
    #pragma unroll
    for (int kb = 0; kb < 4; ++kb) {
      bf16x8 a[2];
      #pragma unroll
      for (int mt = 0; mt < 2; ++mt) {
        int r = mt * 16 + l15;
        a[mt] = *(const bf16x8*)(&a_lds[r * 128 + (((kb * 4 + q) ^ (r & 7)) << 3)]);
      }
      #pragma unroll
      for (int t = 0; t < 2; ++t) {
        int n = (wv * 2 + t) * 16 + l15;
        bf16x8 b = *(const bf16x8*)(Wb + (size_t)n * 128 + kb * 32 + q * 8);
        #pragma unroll
        for (int mt = 0; mt < 2; ++mt)
          acc[mt][t] = __builtin_amdgcn_mfma_f32_16x16x32_bf16(a[mt], b, acc[mt][t], 0, 0, 0);
      }
    }
  }

  #pragma unroll
  for (int mt = 0; mt < 2; ++mt)
    #pragma unroll
    for (int r = 0; r < 4; ++r) {
      int row = v0 + mt * 16 + q * 4 + r;
      if (row < V_NODES) {
        #pragma unroll
        for (int t = 0; t < 2; ++t) {
          int col = (wv * 2 + t) * 16 + l15;
          out[(size_t)row * 128 + col] = fmaxf(acc[mt][t][r], 0.f);
        }
      }
    }
}

// ---------------- fallback edge kernel (round-0, proven 637us) -------------

__global__ __launch_bounds__(256) void edge_k(
    const bf16* __restrict__ embB,
    const int* __restrict__ a0, const int* __restrict__ a1,
    const int* __restrict__ a2, const int* __restrict__ a3,
    const bf16* __restrict__ w1t, const bf16* __restrict__ w2t,
    float* __restrict__ out) {

  __shared__ __attribute__((aligned(16))) bf16 w1_lds[128 * 256];
  __shared__ __attribute__((aligned(16))) bf16 h_lds[64 * 128];

  const int tid = threadIdx.x;
  const int g  = blockIdx.x >> 6;
  const int bs = blockIdx.x & 63;
  const int l = g >> 1, ep = g & 1;
  const int* __restrict__ adj = (l == 0) ? a0 : (l == 1) ? a1 : (l == 2) ? a2 : a3;

  {
    const uint4* w1g = (const uint4*)(w1t + (size_t)g * 128 * 256);
    #pragma unroll
    for (int i = 0; i < 16; ++i) {
      int j = i * 256 + tid;
      int n = j >> 5, c = j & 31;
      *(uint4*)(&w1_lds[n * 256 + ((c ^ (n & 7)) << 3)]) = w1g[j];
    }
  }
  __syncthreads();

  const int w    = tid >> 6;
  const int lane = tid & 63;
  const int wr = w >> 1, wc = w & 1;
  const int l15 = lane & 15, q = lane >> 4;
  const bf16* __restrict__ w2g = w2t + (size_t)g * 128 * 128;

  for (int t = bs; t < 2500; t += 64) {
    const int ebase = t * 64;
    int2 pr0 = ((const int2*)adj)[ebase + 32 * wr + l15];
    int2 pr1 = ((const int2*)adj)[ebase + 32 * wr + 16 + l15];
    pr0.x = clampV(pr0.x); pr0.y = clampV(pr0.y);
    pr1.x = clampV(pr1.x); pr1.y = clampV(pr1.y);

    f32x4 acc[2][4] = {};
    #pragma unroll
    for (int kb = 0; kb < 8; ++kb) {
      const int k = kb * 32 + q * 8;
      const int klo = k & 127;
      const int n0 = (kb < 4) ? pr0.x : pr0.y;
      const int n1 = (kb < 4) ? pr1.x : pr1.y;
      bf16x8 a[2], b[4];
      a[0] = *(const bf16x8*)(embB + (size_t)n0 * 128 + klo);
      a[1] = *(const bf16x8*)(embB + (size_t)n1 * 128 + klo);
      const int csw = ((kb << 2) + q);
      #pragma unroll
      for (int nt = 0; nt < 4; ++nt) {
        int n = 64 * wc + 16 * nt + l15;
        b[nt] = *(const bf16x8*)(&w1_lds[n * 256 + ((csw ^ (l15 & 7)) << 3)]);
      }
      #pragma unroll
      for (int mt = 0; mt < 2; ++mt)
        #pragma unroll
        for (int nt = 0; nt < 4; ++nt)
          acc[mt][nt] = __builtin_amdgcn_mfma_f32_16x16x32_bf16(a[mt], b[nt], acc[mt][nt], 0, 0, 0);
    }

    __syncthreads();
    #pragma unroll
    for (int mt = 0; mt < 2; ++mt)
      #pragma unroll
      for (int nt = 0; nt < 4; ++nt)
        #pragma unroll
        for (int r = 0; r < 4; ++r) {
          float v = acc[mt][nt][r];
          v = v > 0.f ? v : 0.f;
          int row = 32 * wr + 16 * mt + 4 * q + r;
          int col = 64 * wc + 16 * nt + l15;
          int c = col >> 3;
          h_lds[row * 128 + (((c ^ (row & 7)) << 3) | (col & 7))] = (bf16)v;
        }
    __syncthreads();

    f32x4 acc2[2][4] = {};
    #pragma unroll
    for (int kb = 0; kb < 4; ++kb) {
      const int k = kb * 32 + q * 8;
      const int csw = (kb << 2) + q;
      bf16x8 a[2], b[4];
      #pragma unroll
      for (int mt = 0; mt < 2; ++mt) {
        int row = 32 * wr + 16 * mt + l15;
        a[mt] = *(const bf16x8*)(&h_lds[row * 128 + ((csw ^ (row & 7)) << 3)]);
      }
      #pragma unroll
      for (int nt = 0; nt < 4; ++nt) {
        int n = 64 * wc + 16 * nt + l15;
        b[nt] = *(const bf16x8*)(w2g + n * 128 + k);
      }
      #pragma unroll
      for (int mt = 0; mt < 2; ++mt)
        #pragma unroll
        for (int nt = 0; nt < 4; ++nt)
          acc2[mt][nt] = __builtin_amdgcn_mfma_f32_16x16x32_bf16(a[mt], b[nt], acc2[mt][nt], 0, 0, 0);
    }

    #pragma unroll
    for (int mt = 0; mt < 2; ++mt)
      #pragma unroll
      for (int r = 0; r < 4; ++r) {
        int row = 32 * wr + 16 * mt + 4 * q + r;
        int2 pr = ((const int2*)adj)[ebase + row];
        int node = clampV(ep ? pr.y : pr.x);
        float* basep = out + (size_t)node * 128 + 64 * wc + l15;
        #pragma unroll
        for (int nt = 0; nt < 4; ++nt)
          unsafeAtomicAdd(basep + 16 * nt, acc2[mt][nt][r]);
      }
  }
}

// ---------------- host launch ----------------------------------------------

extern "C" void kernel_launch(void* const* d_in, const int* in_sizes, int n_in,
                              void* d_out, int out_size, void* d_ws, size_t ws_size,
                              hipStream_t stream) {
  const float* emb = (const float*)d_in[0];
  const int* a0 = (const int*)d_in[1];
  const int* a1 = (const int*)d_in[2];
  const int* a2 = (const int*)d_in[3];
  const int* a3 = (const int*)d_in[4];
  const float* W1 = (const float*)d_in[5];
  const float* W2 = (const float*)d_in[6];
  float* out = (float*)d_out;

  char* ws = (char*)d_ws;
  bf16* embB   = (bf16*)(ws);                    // 12,800,000
  bf16* w1t    = (bf16*)(ws + 12800000);         //    524,288
  bf16* w2t    = (bf16*)(ws + 13324288);         //    262,144
  int*  offs   = (int*) (ws + 13586432);         //  1,600,016 (400001 ints + pad)
  int2* ids2   = (int2*)(ws + 15186448);         // 10,240,000
  int*  bsums  = (int*) (ws + 25426448);         //      3,136
  int*  counts = (int*) (ws + 25429584);         //  1,600,000 (reused as cursor)
  bf16* HaggB  = (bf16*)(ws + 27029584);         // 102,400,000 (all 8 groups, bf16)
  bf16* Xab    = (bf16*)(ws + 129429584);        // GG * 25,600,000 (Xa|Xb per g)
  const size_t fixedsz = 129429584;

  prep_emb_k<<<6250, 256, 0, stream>>>(emb, embB);
  prep_w1_k<<<1024, 256, 0, stream>>>(W1, w1t);
  prep_w2_k<<<512, 256, 0, stream>>>(W2, w2t);

  int GG = 0;
  if      (ws_size >= fixedsz + 8ull * 25600000) GG = 8;   // 334.2 MB
  else if (ws_size >= fixedsz + 4ull * 25600000) GG = 4;   // 231.8 MB
  else if (ws_size >= fixedsz + 2ull * 25600000) GG = 2;   // 180.6 MB
  else if (ws_size >= fixedsz + 1ull * 25600000) GG = 1;   // 155.0 MB

  if (GG) {
    // CSR build (all 8 groups at once), pairs packed at scatter time
    hipMemsetAsync(counts, 0, 1600000, stream);
    hist_k<<<dim3(625, 8), 256, 0, stream>>>(a0, a1, a2, a3, counts);
    scan_a_k<<<NBLK_SCAN, 256, 0, stream>>>(counts, offs, bsums);
    scan_b_k<<<1, 256, 0, stream>>>(bsums, offs);
    scan_c_k<<<1563, 256, 0, stream>>>(offs, bsums);
    hipMemsetAsync(counts, 0, 1600000, stream);     // reuse counts as cursor
    scatter_ids2_k<<<dim3(625, 8), 256, 0, stream>>>(a0, a1, a2, a3, offs, counts, ids2);

    for (int gb = 0; gb < 8; gb += GG) {
      xgemm2_k<<<dim3(625, GG), 256, 0, stream>>>(embB, w1t, Xab, gb);
      aggf4_k<<<dim3(6250, GG), 256, 0, stream>>>(Xab, offs, ids2, HaggB, gb);
    }
    gemm2p_k<<<1563, 256, 0, stream>>>(HaggB, w2t, out);
  } else {
    hipMemsetAsync(d_out, 0, 25600000, stream);
    edge_k<<<512, 256, 0, stream>>>(embB, a0, a1, a2, a3, w1t, w2t, out);
    relu_k<<<6250, 256, 0, stream>>>(out);
  }
}